// Round 1
// baseline (164.934 us; speedup 1.0000x reference)
//
#include <hip/hip_runtime.h>

// KnowledgeConsistentAttention fused kernel (MI355X / gfx950)
//
// Key identity: sumpool3x3(scores)[b,p,q] = kern[b,p,:] . G[b,:,q]
// with G = sumpool3x3(foreground). So the whole op is flash-attention:
//   K = V = kern (L2-normalized fg columns + eps), Q = G columns, d = 64.
// out[b,c,q] = sum_p kern[p,c] * softmax_p(kern . G[:,q])

typedef __bf16 bf16_t;
typedef __bf16 bf16x8 __attribute__((ext_vector_type(8)));
typedef float f32x4 __attribute__((ext_vector_type(4)));

#define HW_ 4096   // 64*64 spatial positions
#define CH 64      // channels

// XOR-swizzled byte offset into a [64 rows][64 bf16] LDS tile (128 B rows).
// Keeps ds_read_b128 fragment loads (16 lanes, 16 different rows, same col
// range) conflict-free (G4: row-major D=128B is otherwise a 16-way conflict).
__device__ __forceinline__ int swz(int row, int col) {
  return row * 128 + ((col * 2) ^ ((row & 7) << 4));
}

__global__ __launch_bounds__(256, 1) void kca_fused(const float* __restrict__ fg,
                                                    float* __restrict__ out) {
  const int b  = blockIdx.x >> 6;   // batch
  const int y  = blockIdx.x & 63;   // image row -> 64 queries q = y*64 + x
  const int t  = threadIdx.x;
  const int lane = t & 63;
  const int wv   = t >> 6;          // wave id 0..3
  const int l15  = lane & 15;
  const int lg   = lane >> 4;       // lane group 0..3

  const float* F  = fg  + b * (CH * HW_);   // F[c][4096] row-major
  float*       Ob = out + b * (CH * HW_);

  __shared__ __align__(16) char GtB[64 * 128];  // G^T  [q][c] bf16 (swizzled)
  __shared__ __align__(16) char KpB[64 * 128];  // kern [p][c] bf16 (swizzled)
  __shared__ __align__(16) char KtB[64 * 128];  // kern^T [c][p] bf16 (swizzled)
  __shared__ __align__(16) char PtB[64 * 128];  // P^T  [q][p] bf16 (swizzled)
  __shared__ float SF[64][68];                  // S staging f32 (+4 pad)
  __shared__ float red4[4][64];
  __shared__ float mbuf[64], lbuf[64], rbuf[64], nbuf[64];

  // ---- prologue: Gt[x][c] = 3x3 zero-padded sum pool of F at (y, x) ----
  {
    const int x  = t & 63;
    const int c0 = t >> 6;
#pragma unroll
    for (int i = 0; i < 16; ++i) {
      int c = c0 + 4 * i;
      const float* Fc = F + c * HW_;
      float s = 0.f;
      for (int dy = -1; dy <= 1; ++dy) {
        int yy = y + dy;
        if (yy < 0 || yy >= 64) continue;
        const float* r = Fc + yy * 64;
        float v = r[x];
        if (x > 0)  v += r[x - 1];
        if (x < 63) v += r[x + 1];
        s += v;
      }
      *(bf16_t*)(GtB + swz(x, c)) = (bf16_t)s;
    }
    if (t < 64) { mbuf[t] = -INFINITY; lbuf[t] = 0.f; }
  }
  __syncthreads();

  f32x4 oacc[4];
#pragma unroll
  for (int f = 0; f < 4; ++f) { oacc[f][0]=0.f; oacc[f][1]=0.f; oacc[f][2]=0.f; oacc[f][3]=0.f; }

  for (int p0 = 0; p0 < HW_; p0 += 64) {
    const int j  = t & 63;    // local p (column of F block this thread owns)
    const int c0 = t >> 6;

    // Phase A: load F columns (coalesced: consecutive t -> consecutive j)
    float vreg[16];
    float ssq = 0.f;
#pragma unroll
    for (int i = 0; i < 16; ++i) {
      int c = c0 + 4 * i;
      float v = F[c * HW_ + p0 + j] + 1e-7f;
      vreg[i] = v;
      ssq = fmaf(v, v, ssq);
    }
    red4[c0][j] = ssq;
    __syncthreads();                                   // (1)
    if (t < 64) {
      float s = red4[0][t] + red4[1][t] + red4[2][t] + red4[3][t];
      nbuf[t] = 1.0f / sqrtf(s);
    }
    __syncthreads();                                   // (2)

    // Phase B: write kern and kern^T (bf16, swizzled)
    {
      float rn = nbuf[j];
#pragma unroll
      for (int i = 0; i < 16; ++i) {
        int c = c0 + 4 * i;
        bf16_t kv = (bf16_t)(vreg[i] * rn);
        *(bf16_t*)(KpB + swz(j, c)) = kv;   // kern[p][c]
        *(bf16_t*)(KtB + swz(c, j)) = kv;   // kern^T[c][p]
      }
    }
    __syncthreads();                                   // (3)

    // Phase C: GEMM1  S[16*wv + r][q] = kern . G   (K = 64 channels)
    {
      bf16x8 a0 = *(const bf16x8*)(KpB + swz(16 * wv + l15, 8 * lg));
      bf16x8 a1 = *(const bf16x8*)(KpB + swz(16 * wv + l15, 32 + 8 * lg));
#pragma unroll
      for (int f = 0; f < 4; ++f) {
        bf16x8 b0 = *(const bf16x8*)(GtB + swz(16 * f + l15, 8 * lg));
        bf16x8 b1 = *(const bf16x8*)(GtB + swz(16 * f + l15, 32 + 8 * lg));
        f32x4 acc = {0.f, 0.f, 0.f, 0.f};
        acc = __builtin_amdgcn_mfma_f32_16x16x32_bf16(a0, b0, acc, 0, 0, 0);
        acc = __builtin_amdgcn_mfma_f32_16x16x32_bf16(a1, b1, acc, 0, 0, 0);
        // C/D layout (m89-verified): q = 16f + l15, p = 16*wv + 4*lg + r
#pragma unroll
        for (int r = 0; r < 4; ++r) SF[16 * wv + 4 * lg + r][16 * f + l15] = acc[r];
      }
    }
    __syncthreads();                                   // (4)

    // Phase D: online softmax over p (per column q)
    const int q  = t & 63;
    const int pc = (t >> 6) * 16;
    float mloc = -INFINITY;
#pragma unroll
    for (int i = 0; i < 16; ++i) mloc = fmaxf(mloc, SF[pc + i][q]);
    red4[t >> 6][q] = mloc;
    __syncthreads();                                   // (5)
    if (t < 64) {
      float mold = mbuf[t];
      float mnew = fmaxf(fmaxf(red4[0][t], red4[1][t]), fmaxf(red4[2][t], red4[3][t]));
      mnew = fmaxf(mold, mnew);
      rbuf[t] = __expf(mold - mnew);   // 0 on first tile (mold = -inf)
      mbuf[t] = mnew;
    }
    __syncthreads();                                   // (6)
    {
      float mnew = mbuf[q];
      float sloc = 0.f;
#pragma unroll
      for (int i = 0; i < 16; ++i) {
        float e = __expf(SF[pc + i][q] - mnew);
        sloc += e;
        *(bf16_t*)(PtB + swz(q, pc + i)) = (bf16_t)e;  // P^T[q][p]
      }
      red4[t >> 6][q] = sloc;
      // rescale O accumulators by exp(m_old - m_new)
#pragma unroll
      for (int f = 0; f < 4; ++f) {
        float r = rbuf[16 * f + l15];
        oacc[f][0] *= r; oacc[f][1] *= r; oacc[f][2] *= r; oacc[f][3] *= r;
      }
    }
    __syncthreads();                                   // (7)
    if (t < 64) {
      lbuf[t] = lbuf[t] * rbuf[t] + (red4[0][t] + red4[1][t] + red4[2][t] + red4[3][t]);
    }

    // Phase E: GEMM2  O[16*wv + r][q] += kern^T . P   (K = 64 local p)
    {
      bf16x8 a0 = *(const bf16x8*)(KtB + swz(16 * wv + l15, 8 * lg));
      bf16x8 a1 = *(const bf16x8*)(KtB + swz(16 * wv + l15, 32 + 8 * lg));
#pragma unroll
      for (int f = 0; f < 4; ++f) {
        bf16x8 b0 = *(const bf16x8*)(PtB + swz(16 * f + l15, 8 * lg));
        bf16x8 b1 = *(const bf16x8*)(PtB + swz(16 * f + l15, 32 + 8 * lg));
        oacc[f] = __builtin_amdgcn_mfma_f32_16x16x32_bf16(a0, b0, oacc[f], 0, 0, 0);
        oacc[f] = __builtin_amdgcn_mfma_f32_16x16x32_bf16(a1, b1, oacc[f], 0, 0, 0);
      }
    }
    __syncthreads();                                   // (8)
  }

  // ---- epilogue: out[c][q] = O / l ----
#pragma unroll
  for (int f = 0; f < 4; ++f) {
    float li = 1.0f / lbuf[16 * f + l15];
#pragma unroll
    for (int r = 0; r < 4; ++r) {
      int c  = 16 * wv + 4 * lg + r;
      int qq = y * 64 + 16 * f + l15;
      Ob[c * HW_ + qq] = oacc[f][r] * li;
    }
  }
}

extern "C" void kernel_launch(void* const* d_in, const int* in_sizes, int n_in,
                              void* d_out, int out_size, void* d_ws, size_t ws_size,
                              hipStream_t stream) {
  const float* fg = (const float*)d_in[0];
  // d_in[1] (masks) is state-only in the reference forward; unused.
  float* out = (float*)d_out;
  hipLaunchKernelGGL(kca_fused, dim3(256), dim3(256), 0, stream, fg, out);
}

// Round 2
// 101.952 us; speedup vs baseline: 1.6178x; 1.6178x over previous
//
#include <hip/hip_runtime.h>

// KnowledgeConsistentAttention v2 (MI355X / gfx950)
// sumpool3x3(scores)[p,q] = kern[p,:] . G[:,q]  with G = sumpool3x3(fg)
// => flash attention, K=V=kern (normalized fg cols + eps), Q = G cols, d=64.
//
// prep:  kern -> ws as Kp[p][c] (swizzled) + Kt[c][p] (swizzled) + Gt[q][c]
// attn:  per wave: 16 queries, Q in regs, in-register online softmax
//        (p lives in lane-local regs + lane-groups -> 2 shfl_xor),
//        K tiles double-buffered in LDS via global_load_lds, 1 barrier/tile.

typedef __bf16 bf16_t;
typedef __bf16 bf16x2 __attribute__((ext_vector_type(2)));
typedef __bf16 bf16x8 __attribute__((ext_vector_type(8)));
typedef float f32x4 __attribute__((ext_vector_type(4)));

#define HW_ 4096
#define CH 64

// byte offset into a [64][64] bf16 tile (128B rows), XOR-swizzled (G4)
__device__ __forceinline__ int swz(int row, int col) {
  return row * 128 + ((col * 2) ^ ((row & 7) << 4));
}

__device__ __forceinline__ void gload_lds16(const void* gsrc, void* lds_dst) {
  __builtin_amdgcn_global_load_lds(
      (const __attribute__((address_space(1))) unsigned int*)gsrc,
      (__attribute__((address_space(3))) unsigned int*)lds_dst, 16, 0, 0);
}

// ---------------- prep: kern + pooled Q, fragment-ready layouts ----------------
__global__ __launch_bounds__(256, 1) void kca_prep(const float* __restrict__ fg,
                                                   char* __restrict__ KpB,
                                                   char* __restrict__ KtB,
                                                   char* __restrict__ GtB) {
  const int b = blockIdx.x >> 6;
  const int y = blockIdx.x & 63;
  const int t = threadIdx.x;
  const int x = t & 63;
  const int c0 = t >> 6;
  const float* F = fg + (size_t)b * (CH * HW_);

  __shared__ bf16_t Ks[64][72];
  __shared__ bf16_t Gs[64][72];
  __shared__ float red[4][64];

  float vreg[16], greg[16];
  float ssq = 0.f;
#pragma unroll
  for (int i = 0; i < 16; ++i) {
    const int c = c0 + 4 * i;
    const float* Fc = F + c * HW_;
    float v = Fc[y * 64 + x] + 1e-7f;
    vreg[i] = v;
    ssq = fmaf(v, v, ssq);
    float s = 0.f;
    for (int dy = -1; dy <= 1; ++dy) {
      int yy = y + dy;
      if (yy < 0 || yy > 63) continue;
      const float* r = Fc + yy * 64;
      float vv = r[x];
      if (x > 0)  vv += r[x - 1];
      if (x < 63) vv += r[x + 1];
      s += vv;
    }
    greg[i] = s;
  }
  red[c0][x] = ssq;
  __syncthreads();
  const float rn = 1.0f / sqrtf(red[0][x] + red[1][x] + red[2][x] + red[3][x]);
#pragma unroll
  for (int i = 0; i < 16; ++i) {
    const int c = c0 + 4 * i;
    Ks[x][c] = (bf16_t)(vreg[i] * rn);
    Gs[x][c] = (bf16_t)greg[i];
  }
  __syncthreads();

  char* Kp_b = KpB + (size_t)b * (HW_ * CH * 2) + (size_t)y * 8192;
  char* Gt_b = GtB + (size_t)b * (HW_ * CH * 2) + (size_t)y * 8192;
  char* Kt_b = KtB + (size_t)b * (CH * HW_ * 2) + (size_t)y * 128;
#pragma unroll
  for (int o = t * 16; o < 8192; o += 4096) {
    const int row  = o >> 7;        // p-local for Kp/Gt; c for Kt
    const int colb = o & 127;
    const int se   = (colb ^ ((row & 7) << 4)) >> 1;  // unswizzled source elem
    *(bf16x8*)(Kp_b + o) = *(const bf16x8*)&Ks[row][se];           // swizzled
    *(bf16x8*)(Gt_b + o) = *(const bf16x8*)&Gs[row][colb >> 1];    // linear
    bf16x8 tv;
#pragma unroll
    for (int j = 0; j < 8; ++j) tv[j] = Ks[se + j][row];
    *(bf16x8*)(Kt_b + (size_t)row * 8192 + colb) = tv;             // swizzled
  }
}

// ---------------- main: fused flash attention ----------------
__global__ __launch_bounds__(256, 1) void kca_attn(const char* __restrict__ KpB,
                                                   const char* __restrict__ KtB,
                                                   const char* __restrict__ GtB,
                                                   float* __restrict__ out) {
  const int b   = blockIdx.x >> 6;
  const int y   = blockIdx.x & 63;
  const int t   = threadIdx.x;
  const int lane = t & 63;
  const int wv   = t >> 6;
  const int l15  = lane & 15;
  const int lg   = lane >> 4;

  const char* Kp_b = KpB + (size_t)b * (HW_ * CH * 2);
  const char* Kt_b = KtB + (size_t)b * (CH * HW_ * 2);
  const char* Gt_b = GtB + (size_t)b * (HW_ * CH * 2);
  float* Ob = out + (size_t)b * (CH * HW_);

  __shared__ __align__(16) char KpT[2][8192];
  __shared__ __align__(16) char KtT[2][8192];
  __shared__ __align__(16) char Pt[8192];

  // Q fragments, held in registers for the whole kernel (wave's 16 queries)
  const char* qrow = Gt_b + (size_t)(y * 64 + 16 * wv + l15) * 128;
  const bf16x8 qb0 = *(const bf16x8*)(qrow + 16 * lg);
  const bf16x8 qb1 = *(const bf16x8*)(qrow + 64 + 16 * lg);

  f32x4 oacc[4];
#pragma unroll
  for (int mt = 0; mt < 4; ++mt) { oacc[mt][0]=0.f; oacc[mt][1]=0.f; oacc[mt][2]=0.f; oacc[mt][3]=0.f; }
  float m_run = -INFINITY, l_run = 0.f;

  const int qr = 16 * wv + l15;      // wave-private P^T row

  // stage helper: Kp tile contiguous 8KB; Kt tile 64 rows x 128B from 8KB pitch
#define STAGE(BUF, P0)                                                          \
  do {                                                                          \
    const char* _ksrc = Kp_b + (size_t)(P0) * 128;                              \
    gload_lds16(_ksrc + t * 16,        &KpT[BUF][t * 16]);                      \
    gload_lds16(_ksrc + 4096 + t * 16, &KpT[BUF][4096 + t * 16]);               \
    const int _r0 = t >> 3, _cb = (t & 7) * 16;                                 \
    const char* _tsrc = Kt_b + (size_t)(P0) * 2 + _cb;                          \
    gload_lds16(_tsrc + (size_t)_r0 * 8192,        &KtT[BUF][t * 16]);          \
    gload_lds16(_tsrc + (size_t)(_r0 + 32) * 8192, &KtT[BUF][4096 + t * 16]);   \
  } while (0)

  STAGE(0, 0);
  int cur = 0;
  for (int it = 0; it < 64; ++it) {
    __syncthreads();                         // staged buf[cur] ready
    if (it + 1 < 64) STAGE(cur ^ 1, (it + 1) * 64);

    // ---- GEMM1: S[p=16f+4lg+r][q=16wv+l15] ----
    f32x4 s[4];
#pragma unroll
    for (int f = 0; f < 4; ++f) {
      const int row = 16 * f + l15;
      bf16x8 a0 = *(const bf16x8*)(&KpT[cur][swz(row, 8 * lg)]);
      bf16x8 a1 = *(const bf16x8*)(&KpT[cur][swz(row, 32 + 8 * lg)]);
      f32x4 z = {0.f, 0.f, 0.f, 0.f};
      z = __builtin_amdgcn_mfma_f32_16x16x32_bf16(a0, qb0, z, 0, 0, 0);
      z = __builtin_amdgcn_mfma_f32_16x16x32_bf16(a1, qb1, z, 0, 0, 0);
      s[f] = z;
    }

    // ---- in-register online softmax (reduce over lane-groups) ----
    float mloc = s[0][0];
#pragma unroll
    for (int f = 0; f < 4; ++f)
#pragma unroll
      for (int r = 0; r < 4; ++r) mloc = fmaxf(mloc, s[f][r]);
    mloc = fmaxf(mloc, __shfl_xor(mloc, 16));
    mloc = fmaxf(mloc, __shfl_xor(mloc, 32));
    const float mnew  = fmaxf(m_run, mloc);
    const float scale = __expf(m_run - mnew);   // 0 on first tile
    m_run = mnew;

    float lsum = 0.f;
#pragma unroll
    for (int f = 0; f < 4; ++f) {
#pragma unroll
      for (int rp = 0; rp < 2; ++rp) {
        float e0 = __expf(s[f][2 * rp]     - mnew);
        float e1 = __expf(s[f][2 * rp + 1] - mnew);
        lsum += e0 + e1;
        bf16x2 pk; pk[0] = (bf16_t)e0; pk[1] = (bf16_t)e1;
        *(bf16x2*)(&Pt[swz(qr, 16 * f + 4 * lg + 2 * rp)]) = pk;  // wave-private row
      }
    }
    lsum += __shfl_xor(lsum, 16);
    lsum += __shfl_xor(lsum, 32);
    l_run = l_run * scale + lsum;
#pragma unroll
    for (int mt = 0; mt < 4; ++mt) {
      oacc[mt][0] *= scale; oacc[mt][1] *= scale;
      oacc[mt][2] *= scale; oacc[mt][3] *= scale;
    }

    // ---- GEMM2: O[c=16mt+4lg+r][q] += kern^T . P ----
    bf16x8 pb0 = *(const bf16x8*)(&Pt[swz(qr, 8 * lg)]);
    bf16x8 pb1 = *(const bf16x8*)(&Pt[swz(qr, 32 + 8 * lg)]);
#pragma unroll
    for (int mt = 0; mt < 4; ++mt) {
      const int row = 16 * mt + l15;
      bf16x8 a0 = *(const bf16x8*)(&KtT[cur][swz(row, 8 * lg)]);
      bf16x8 a1 = *(const bf16x8*)(&KtT[cur][swz(row, 32 + 8 * lg)]);
      oacc[mt] = __builtin_amdgcn_mfma_f32_16x16x32_bf16(a0, pb0, oacc[mt], 0, 0, 0);
      oacc[mt] = __builtin_amdgcn_mfma_f32_16x16x32_bf16(a1, pb1, oacc[mt], 0, 0, 0);
    }
    cur ^= 1;
  }

  const float li = 1.0f / l_run;
#pragma unroll
  for (int mt = 0; mt < 4; ++mt)
#pragma unroll
    for (int r = 0; r < 4; ++r)
      Ob[(size_t)(16 * mt + 4 * lg + r) * HW_ + y * 64 + 16 * wv + l15] = oacc[mt][r] * li;
#undef STAGE
}

extern "C" void kernel_launch(void* const* d_in, const int* in_sizes, int n_in,
                              void* d_out, int out_size, void* d_ws, size_t ws_size,
                              hipStream_t stream) {
  const float* fg = (const float*)d_in[0];
  float* out = (float*)d_out;
  char* ws = (char*)d_ws;
  char* Kp = ws;                 // 2 MB (4 x 4096 x 64 bf16, swizzled rows)
  char* Kt = ws + (2u << 20);    // 2 MB (4 x 64 x 4096 bf16, swizzled rows)
  char* Gt = ws + (4u << 20);    // 2 MB (4 x 4096 x 64 bf16, linear)
  hipLaunchKernelGGL(kca_prep, dim3(256), dim3(256), 0, stream, fg, Kp, Kt, Gt);
  hipLaunchKernelGGL(kca_attn, dim3(256), dim3(256), 0, stream, Kp, Kt, Gt, out);
}

// Round 3
// 66.164 us; speedup vs baseline: 2.4928x; 1.5409x over previous
//
#include <hip/hip_runtime.h>

// KnowledgeConsistentAttention v3 (MI355X / gfx950)
// sumpool3x3(scores)[p,q] = kern[p,:] . G[:,q], G = sumpool3x3(fg)
// => flash attention, K=V=kern (normalized fg cols + eps), Q = G cols, d=64.
//
// v3: 1024-thread blocks (16 waves = 4/SIMD). 4 key-groups of 4 waves each,
// p split 4x -> 32 sequential tiles of 32 keys; in-LDS m/l/O combine at end.
// Global Kp/Kt/Gt linear; XOR swizzle folded into global_load_lds source addr.

typedef __bf16 bf16_t;
typedef __bf16 bf16x2 __attribute__((ext_vector_type(2)));
typedef __bf16 bf16x8 __attribute__((ext_vector_type(8)));
typedef float f32x4 __attribute__((ext_vector_type(4)));

#define HW_ 4096
#define CH 64

__device__ __forceinline__ void gload_lds16(const void* gsrc, void* lds_dst) {
  __builtin_amdgcn_global_load_lds(
      (const __attribute__((address_space(1))) unsigned int*)gsrc,
      (__attribute__((address_space(3))) unsigned int*)lds_dst, 16, 0, 0);
}

// ---------------- prep: kern + pooled Q (all linear layouts) ----------------
__global__ __launch_bounds__(512, 1) void kca_prep(const float* __restrict__ fg,
                                                   char* __restrict__ KpB,
                                                   char* __restrict__ KtB,
                                                   char* __restrict__ GtB) {
  const int b = blockIdx.x >> 6, y = blockIdx.x & 63;
  const int t = threadIdx.x;
  const int x = t & 63, c0 = t >> 6;  // c0 in 0..7
  const float* F = fg + (size_t)b * (CH * HW_);

  __shared__ float  Ft[3][64][64];   // fg rows y-1..y+1, all channels
  __shared__ bf16_t Ks[64][72];      // kern[x][c]
  __shared__ bf16_t Gs[64][72];      // G[x][c]
  __shared__ float  red[8][64];

  float* Ftf = &Ft[0][0][0];
#pragma unroll
  for (int k = 0; k < 24; ++k) {
    const int o = t + 512 * k;
    const int yy = o >> 12, cc = (o >> 6) & 63, xx = o & 63;
    const int gy = y - 1 + yy;
    Ftf[o] = (gy >= 0 && gy <= 63) ? F[cc * HW_ + gy * 64 + xx] : 0.f;
  }
  __syncthreads();

  float vreg[8], greg[8], ssq = 0.f;
#pragma unroll
  for (int i = 0; i < 8; ++i) {
    const int c = c0 + 8 * i;
    float v = Ft[1][c][x] + 1e-7f;
    vreg[i] = v; ssq = fmaf(v, v, ssq);
    float s = 0.f;
#pragma unroll
    for (int yy = 0; yy < 3; ++yy) {
      const float* r = &Ft[yy][c][0];
      float vv = r[x];
      if (x > 0)  vv += r[x - 1];
      if (x < 63) vv += r[x + 1];
      s += vv;
    }
    greg[i] = s;
  }
  red[c0][x] = ssq;
  __syncthreads();
  float tot = 0.f;
#pragma unroll
  for (int k = 0; k < 8; ++k) tot += red[k][x];
  const float rn = 1.0f / sqrtf(tot);
#pragma unroll
  for (int i = 0; i < 8; ++i) {
    const int c = c0 + 8 * i;
    Ks[x][c] = (bf16_t)(vreg[i] * rn);
    Gs[x][c] = (bf16_t)greg[i];
  }
  __syncthreads();

  char* Kp_b = KpB + (size_t)b * (HW_ * CH * 2) + (size_t)y * 8192;  // [p][c]
  char* Gt_b = GtB + (size_t)b * (HW_ * CH * 2) + (size_t)y * 8192;  // [q][c]
  char* Kt_b = KtB + (size_t)b * (CH * HW_ * 2) + (size_t)y * 128;   // [c][p]
  const int row = t >> 3, colb = (t & 7) * 16;
  *(bf16x8*)(Kp_b + t * 16) = *(const bf16x8*)&Ks[row][colb >> 1];
  *(bf16x8*)(Gt_b + t * 16) = *(const bf16x8*)&Gs[row][colb >> 1];
  bf16x8 tv;
#pragma unroll
  for (int j = 0; j < 8; ++j) tv[j] = Ks[(colb >> 1) + j][row];
  *(bf16x8*)(Kt_b + (size_t)row * 8192 + colb) = tv;
}

// ---------------- main: fused flash attention, 4-way key-split ----------------
__global__ __launch_bounds__(1024, 1) void kca_attn(const char* __restrict__ KpB,
                                                    const char* __restrict__ KtB,
                                                    const char* __restrict__ GtB,
                                                    float* __restrict__ out) {
  const int b = blockIdx.x >> 6, y = blockIdx.x & 63;
  const int t = threadIdx.x;
  const int g  = t >> 8;           // key-group 0..3
  const int tl = t & 255;          // thread within group
  const int lane = t & 63;
  const int wv   = (t >> 6) & 3;   // wave within group
  const int l15  = lane & 15, lg = lane >> 4;

  const char* Kp_b = KpB + (size_t)b * (HW_ * CH * 2);
  const char* Kt_b = KtB + (size_t)b * (CH * HW_ * 2);
  const char* Gt_b = GtB + (size_t)b * (HW_ * CH * 2);
  float* Ob = out + (size_t)b * (CH * HW_);

  __shared__ __align__(16) char SM[81920];   // Kp 32K | Kt 32K | Pt 16K
  __shared__ float mlm[4][64], mll[4][64], linv[64];

  char* myKp = SM + g * 8192;            // [2][4096]: [32 p][128B swz rows]
  char* myKt = SM + 32768 + g * 8192;    // [2][4096]: [64 c][64B swz rows]
  char* myPt = SM + 65536 + g * 4096;    // [64 q][64B swz rows]

  // Q fragments in registers for the whole kernel (wave's 16 queries)
  const char* qrow = Gt_b + (size_t)(y * 64 + 16 * wv + l15) * 128;
  const bf16x8 qb0 = *(const bf16x8*)(qrow + 16 * lg);
  const bf16x8 qb1 = *(const bf16x8*)(qrow + 64 + 16 * lg);

  f32x4 oacc[4];
#pragma unroll
  for (int mt = 0; mt < 4; ++mt) { oacc[mt][0]=0.f; oacc[mt][1]=0.f; oacc[mt][2]=0.f; oacc[mt][3]=0.f; }
  float m_run = -INFINITY, l_run = 0.f;

  const int qr  = 16 * wv + l15;
  const int qsw = (qr & 3) << 4;
  char* prow = myPt + qr * 64;

  const int sr1 = tl >> 3, scb1 = (tl & 7) * 16;   // Kp stage: 32 rows x 128B
  const int sr2 = tl >> 2, scb2 = (tl & 3) * 16;   // Kt stage: 64 rows x 64B

#define STAGE(D, P0)                                                                    \
  do {                                                                                  \
    gload_lds16(Kp_b + (size_t)((P0) + sr1) * 128 + (scb1 ^ ((sr1 & 7) << 4)),          \
                myKp + (D) * 4096 + tl * 16);                                           \
    gload_lds16(Kt_b + (size_t)sr2 * 8192 + (size_t)(P0) * 2 + (scb2 ^ ((sr2 & 3) << 4)), \
                myKt + (D) * 4096 + tl * 16);                                           \
  } while (0)

  const int pbase = g * 1024;
  STAGE(0, pbase);
  int cur = 0;
  for (int it = 0; it < 32; ++it) {
    __syncthreads();                                   // buf[cur] staged
    if (it + 1 < 32) STAGE(cur ^ 1, pbase + (it + 1) * 32);

    // ---- GEMM1: S[p = 16f+4lg+r][q = l15] over K=64 channels ----
    f32x4 s0, s1;
    {
      const char* kp = myKp + cur * 4096;
      int r = l15, sw = (r & 7) << 4;
      bf16x8 a0 = *(const bf16x8*)(kp + r * 128 + ((16 * lg) ^ sw));
      bf16x8 a1 = *(const bf16x8*)(kp + r * 128 + ((64 + 16 * lg) ^ sw));
      f32x4 z = {0.f, 0.f, 0.f, 0.f};
      z = __builtin_amdgcn_mfma_f32_16x16x32_bf16(a0, qb0, z, 0, 0, 0);
      z = __builtin_amdgcn_mfma_f32_16x16x32_bf16(a1, qb1, z, 0, 0, 0);
      s0 = z;
      r = 16 + l15; sw = (r & 7) << 4;
      a0 = *(const bf16x8*)(kp + r * 128 + ((16 * lg) ^ sw));
      a1 = *(const bf16x8*)(kp + r * 128 + ((64 + 16 * lg) ^ sw));
      f32x4 z1 = {0.f, 0.f, 0.f, 0.f};
      z1 = __builtin_amdgcn_mfma_f32_16x16x32_bf16(a0, qb0, z1, 0, 0, 0);
      z1 = __builtin_amdgcn_mfma_f32_16x16x32_bf16(a1, qb1, z1, 0, 0, 0);
      s1 = z1;
    }

    // ---- online softmax (8 lane-local vals + 2 shfl over lane-groups) ----
    float mloc = fmaxf(fmaxf(fmaxf(s0[0], s0[1]), fmaxf(s0[2], s0[3])),
                       fmaxf(fmaxf(s1[0], s1[1]), fmaxf(s1[2], s1[3])));
    mloc = fmaxf(mloc, __shfl_xor(mloc, 16));
    mloc = fmaxf(mloc, __shfl_xor(mloc, 32));
    if (!__all(mloc <= m_run)) {       // exact skip-rescale: only when max grows
      const float mnew = fmaxf(m_run, mloc);
      const float sc = __expf(m_run - mnew);   // 0 on first tile
      m_run = mnew; l_run *= sc;
#pragma unroll
      for (int mt = 0; mt < 4; ++mt) {
        oacc[mt][0] *= sc; oacc[mt][1] *= sc; oacc[mt][2] *= sc; oacc[mt][3] *= sc;
      }
    }
    float lsum = 0.f;
#pragma unroll
    for (int f = 0; f < 2; ++f) {
      const f32x4 sv = f ? s1 : s0;
#pragma unroll
      for (int rp = 0; rp < 2; ++rp) {
        float e0 = __expf(sv[2 * rp]     - m_run);
        float e1 = __expf(sv[2 * rp + 1] - m_run);
        lsum += e0 + e1;
        bf16x2 pk; pk[0] = (bf16_t)e0; pk[1] = (bf16_t)e1;
        *(bf16x2*)(prow + ((32 * f + 8 * lg + 4 * rp) ^ qsw)) = pk;
      }
    }
    lsum += __shfl_xor(lsum, 16);
    lsum += __shfl_xor(lsum, 32);
    l_run += lsum;

    // ---- GEMM2: O[c = 16mt+4lg+r][q = l15] += Kt . P over K=32 p ----
    {
      bf16x8 pb = *(const bf16x8*)(prow + ((16 * lg) ^ qsw));
      const char* kt = myKt + cur * 4096;
#pragma unroll
      for (int mt = 0; mt < 4; ++mt) {
        const int r = 16 * mt + l15;
        bf16x8 a = *(const bf16x8*)(kt + r * 64 + ((16 * lg) ^ ((r & 3) << 4)));
        oacc[mt] = __builtin_amdgcn_mfma_f32_16x16x32_bf16(a, pb, oacc[mt], 0, 0, 0);
      }
    }
    cur ^= 1;
  }
#undef STAGE

  // ---- combine 4 key-group partials (tree: g0+g1 -> O1, g2+g3 -> O2) ----
  if (lg == 0) { mlm[g][qr] = m_run; mll[g][qr] = l_run; }
  __syncthreads();                                    // C1: all compute done
  const float mstar = fmaxf(fmaxf(mlm[0][qr], mlm[1][qr]), fmaxf(mlm[2][qr], mlm[3][qr]));
  const float lstar = mll[0][qr] * __expf(mlm[0][qr] - mstar)
                    + mll[1][qr] * __expf(mlm[1][qr] - mstar)
                    + mll[2][qr] * __expf(mlm[2][qr] - mstar)
                    + mll[3][qr] * __expf(mlm[3][qr] - mstar);
  const float a = __expf(m_run - mstar);
  if (g == 0 && lg == 0) linv[qr] = 1.0f / lstar;

  float* O1 = (float*)SM;             // [64][68], reuses dead Kp staging
  float* O2 = (float*)(SM + 32768);   // [64][68], reuses dead Kt staging
  if (g == 0 || g == 2) {
    float* Od = (g == 0) ? O1 : O2;
#pragma unroll
    for (int mt = 0; mt < 4; ++mt)
#pragma unroll
      for (int r = 0; r < 4; ++r)
        Od[(16 * mt + 4 * lg + r) * 68 + qr] = oacc[mt][r] * a;
  }
  __syncthreads();                                    // C2
  if (g == 1 || g == 3) {
    float* Od = (g == 1) ? O1 : O2;
#pragma unroll
    for (int mt = 0; mt < 4; ++mt)
#pragma unroll
      for (int r = 0; r < 4; ++r)
        Od[(16 * mt + 4 * lg + r) * 68 + qr] += oacc[mt][r] * a;
  }
  __syncthreads();                                    // C3
  if (t < 256) {                                      // coalesced f32x4 store
    const int c = t >> 2, qc = (t & 3) * 16;
    const float* r1 = O1 + c * 68 + qc;
    const float* r2 = O2 + c * 68 + qc;
    float* dst = Ob + (size_t)c * HW_ + y * 64 + qc;
#pragma unroll
    for (int j4 = 0; j4 < 4; ++j4) {
      f32x4 v;
#pragma unroll
      for (int j = 0; j < 4; ++j)
        v[j] = (r1[4 * j4 + j] + r2[4 * j4 + j]) * linv[qc + 4 * j4 + j];
      *(f32x4*)(dst + 4 * j4) = v;
    }
  }
}

extern "C" void kernel_launch(void* const* d_in, const int* in_sizes, int n_in,
                              void* d_out, int out_size, void* d_ws, size_t ws_size,
                              hipStream_t stream) {
  const float* fg = (const float*)d_in[0];
  float* out = (float*)d_out;
  char* ws = (char*)d_ws;
  char* Kp = ws;                 // 2 MB  [b][p][c] bf16, linear
  char* Kt = ws + (2u << 20);    // 2 MB  [b][c][p] bf16, linear
  char* Gt = ws + (4u << 20);    // 2 MB  [b][q][c] bf16, linear
  hipLaunchKernelGGL(kca_prep, dim3(256), dim3(512), 0, stream, fg, Kp, Kt, Gt);
  hipLaunchKernelGGL(kca_attn, dim3(256), dim3(1024), 0, stream, Kp, Kt, Gt, out);
}